// Round 12
// baseline (1022.052 us; speedup 1.0000x reference)
//
#include <hip/hip_runtime.h>
#include <math.h>

// Problem constants (fixed by the reference setup)
#define B_SZ   64
#define C_SZ   12
#define T_SZ   2048
#define K_SZ   2048
#define LMAX   11
#define CMAX   11     // C-1
#define PL_PAD 1024
#define A_PARAM 7.0f

#define NW     8      // waves per block in main kernel
#define BLOCK_MAIN (NW * 64)
#define R      8      // outputs per half-wave per item (item covers 2R outputs)

typedef _Float16 h2 __attribute__((ext_vector_type(2)));

// ---------------------------------------------------------------------------
// Pack to batch-pair fp16: xT2[c][t][bp] = {fp16 x[2bp][c][t], fp16 x[2bp+1][c][t]}
// 12*2048*32 u32 = 3.15 MB -> per-XCD L2 resident.
__global__ __launch_bounds__(256) void trp_kernel(const float* __restrict__ x,
                                                  unsigned* __restrict__ xT2) {
    const int u  = blockIdx.x * 256 + threadIdx.x;   // [0, C*T*32)
    const int bp = u & 31;
    const int t  = (u >> 5) & (T_SZ - 1);
    const int c  = u >> 16;                          // T*32 = 65536 per channel
    const float a = x[((size_t)(2 * bp) * C_SZ + c) * T_SZ + t];
    const float b = x[((size_t)(2 * bp + 1) * C_SZ + c) * T_SZ + t];
    h2 v; v.x = (_Float16)a; v.y = (_Float16)b;
    xT2[u] = __builtin_bit_cast(unsigned, v);
}

// ---------------------------------------------------------------------------
// Schedule: cost[k] ~ n*L*ceil(olen/128). Bitonic sort descending (LPT).
__global__ __launch_bounds__(1024) void sched_kernel(const float* __restrict__ w,
                                                     const int* __restrict__ olens,
                                                     unsigned* __restrict__ perm) {
    __shared__ unsigned key[K_SZ];
    const int tid = threadIdx.x;

    for (int k = tid; k < K_SZ; k += 1024) {
        const float* wk = w + (size_t)k * (CMAX * LMAX);
        int n = 0, L = 0;
        for (int e = 0; e < CMAX * LMAX; ++e) {
            if (wk[e] != 0.0f) {
                const int c = e / LMAX, l = e % LMAX;
                n = max(n, c + 1);
                L = max(L, l + 1);
            }
        }
        const unsigned cost = (unsigned)(n * L) * (unsigned)((olens[k] + 127) >> 7);
        key[k] = (cost << 11) | (unsigned)k;
    }
    __syncthreads();

    for (int ksz = 2; ksz <= K_SZ; ksz <<= 1) {
        for (int j = ksz >> 1; j > 0; j >>= 1) {
            for (int i = tid; i < K_SZ; i += 1024) {
                const int ixj = i ^ j;
                if (ixj > i) {
                    const unsigned a = key[i], b = key[ixj];
                    const bool sw = ((i & ksz) == 0) ? (a < b) : (a > b); // descending
                    if (sw) { key[i] = b; key[ixj] = a; }
                }
            }
            __syncthreads();
        }
    }
    for (int i = tid; i < K_SZ; i += 1024)
        perm[i] = key[i] & 0x7FFu;
}

// ---------------------------------------------------------------------------
// Batch-pair pk_fma scheme. Wave lane = h*32 + bp:
//   bp in [0,32): batches {2bp, 2bp+1} packed in one u32 (fp16x2)
//   h in {0,1}:   outputs r + 8h of a 16-output item
// Per channel-item: NV u32 loads (2 batches each), LC*R v_pk_fma_f16, 0 packs.
template<int LC>
__device__ __forceinline__ void conv_all(
    const unsigned* __restrict__ xT2,
    const int*      __restrict__ sCh,
    const unsigned  (* __restrict__ sWs)[LMAX],  // splat {w,w} fp16 pairs
    int n, int d, int offr, int olen, unsigned bias2,
    int bp, int h, int wid,
    float& psum_lo, float& psum_hi, float& pmax_lo, float& pmax_hi)
{
    constexpr int NV   = R + LC - 1;          // taps per half
    constexpr int SPAN = 2 * R + LC - 2;      // max tap index across halves

    const int nj   = (olen + d - 1) / d;              // outputs per residue chain
    const int njb  = (nj + 2 * R - 1) / (2 * R);      // 16-output items per chain
    const int S    = (d >= 64) ? 1 : ((64 + d - 1) / d);
    const int len  = (njb + S - 1) / S;
    const int nunits = d * S;

    const int h8d   = h * (d << 3);           // tap/output shift for half h
    const int voffe = h * (d << 8) + bp;      // fast-path per-lane element offset

    for (int u = wid; u < nunits; u += NW) {
        int q, seg;
        if (S == 1) { q = u; seg = 0; }
        else        { q = u % d; seg = u / d; }       // wave-uniform div
        const int jb0 = seg * len;
        const int jb1 = min(njb, jb0 + len);

        for (int jb = jb0; jb < jb1; ++jb) {
            const int tq = q + jb * (2 * R * d);      // first output t (h=0)
            if (tq >= olen) break;
            const int tpos0 = tq + offr;              // real x coord of tap 0

            h2 y2[R];
            #pragma unroll
            for (int r = 0; r < R; ++r) y2[r] = __builtin_bit_cast(h2, bias2);

            const bool fast = (tpos0 >= 0) && (tpos0 + SPAN * d < T_SZ);

            if (fast) {
                for (int c = 0; c < n; ++c) {
                    const int rb = __builtin_amdgcn_readfirstlane(sCh[c] * T_SZ + tpos0);
                    const unsigned* rp = xT2 + ((size_t)rb << 5);   // uniform base

                    unsigned vp2[NV];
                    #pragma unroll
                    for (int i = 0; i < NV; ++i) {
                        vp2[i] = rp[voffe];                         // saddr + voff
                        rp += (d << 5);                             // SALU bump
                    }
                    const unsigned* wrow = &sWs[c][0];
                    #pragma unroll
                    for (int l = 0; l < LC; ++l) {
                        const h2 w = __builtin_bit_cast(h2, wrow[l]);  // LDS broadcast
                        #pragma unroll
                        for (int r = 0; r < R; ++r)
                            y2[r] = __builtin_elementwise_fma(
                                w, __builtin_bit_cast(h2, vp2[l + r]), y2[r]);
                    }
                }
            } else {
                for (int c = 0; c < n; ++c) {
                    const int rbs = __builtin_amdgcn_readfirstlane(sCh[c] * T_SZ);
                    const unsigned* row = xT2 + ((size_t)rbs << 5);

                    unsigned vp2[NV];
                    #pragma unroll
                    for (int i = 0; i < NV; ++i) {
                        const int tp  = tpos0 + i * d + h8d;        // per-lane (h)
                        const int tpc = min(max(tp, 0), T_SZ - 1);
                        const unsigned v = row[(tpc << 5) + bp];
                        vp2[i] = ((unsigned)tp < (unsigned)T_SZ) ? v : 0u;
                    }
                    const unsigned* wrow = &sWs[c][0];
                    #pragma unroll
                    for (int l = 0; l < LC; ++l) {
                        const h2 w = __builtin_bit_cast(h2, wrow[l]);
                        #pragma unroll
                        for (int r = 0; r < R; ++r)
                            y2[r] = __builtin_elementwise_fma(
                                w, __builtin_bit_cast(h2, vp2[l + r]), y2[r]);
                    }
                }
            }

            #pragma unroll
            for (int r = 0; r < R; ++r) {
                const int tl = tq + r * d + h8d;      // this half's output t
                if (tl < olen) {                      // per-lane predication
                    const float ylo = (float)y2[r].x;
                    const float yhi = (float)y2[r].y;
                    psum_lo += 1.0f / (1.0f + __expf(3.0f - A_PARAM * ylo));
                    psum_hi += 1.0f / (1.0f + __expf(3.0f - A_PARAM * yhi));
                    pmax_lo  = fmaxf(pmax_lo, ylo);
                    pmax_hi  = fmaxf(pmax_hi, yhi);
                }
            }
        }
    }
}

__global__ __launch_bounds__(BLOCK_MAIN, 8) void rocket_tr(
    const unsigned* __restrict__ xT2,        // (C, T, 32) fp16 batch pairs
    const unsigned* __restrict__ perm,       // heavy-first block -> k map
    const float* __restrict__ weights,       // (K, CMAX, LMAX)
    const float* __restrict__ biases,
    const int*   __restrict__ ch_idx,        // (K, CMAX)
    const int*   __restrict__ dils,
    const int*   __restrict__ offs,
    const int*   __restrict__ olens,
    float*       __restrict__ out)           // (B, 2K)
{
    __shared__ float    sW[CMAX][LMAX];
    __shared__ unsigned sWs[CMAX][LMAX];     // splat {w,w} fp16 pairs
    __shared__ int      sCh[CMAX];
    __shared__ int      sMeta[2];
    __shared__ float    sPlo[NW][64];
    __shared__ float    sPhi[NW][64];
    __shared__ float    sMlo[NW][64];
    __shared__ float    sMhi[NW][64];

    const int k   = (int)perm[blockIdx.x];
    const int tid = threadIdx.x;

    if (tid < CMAX * LMAX)
        sW[tid / LMAX][tid % LMAX] = weights[(size_t)k * (CMAX * LMAX) + tid];
    if (tid < CMAX)
        sCh[tid] = ch_idx[(size_t)k * CMAX + tid];
    __syncthreads();

    if (tid < CMAX * LMAX) {
        const int c = tid / LMAX, l = tid % LMAX;
        const _Float16 wh = (_Float16)sW[c][l];
        h2 hh; hh.x = wh; hh.y = wh;
        sWs[c][l] = __builtin_bit_cast(unsigned, hh);
    }
    if (tid == 0) {
        // Effective channel/tap counts (zero-padded rows/taps contribute 0).
        int n = 0, L = 0;
        for (int c = 0; c < CMAX; ++c) {
            bool nz = false;
            for (int l = 0; l < LMAX; ++l) {
                if (sW[c][l] != 0.0f) { nz = true; if (l + 1 > L) L = l + 1; }
            }
            if (nz) n = c + 1;
        }
        sMeta[0] = n; sMeta[1] = L;
    }
    __syncthreads();

    const int   n    = sMeta[0];
    const int   L    = sMeta[1];
    const int   d    = dils[k];
    const int   offr = offs[k] - PL_PAD;   // real x coord offset (may be <0)
    const int   olen = olens[k];
    const float bias = biases[k];
    const int   lane = tid & 63;
    const int   bp   = lane & 31;
    const int   h    = lane >> 5;
    const int   wid  = __builtin_amdgcn_readfirstlane(tid >> 6);

    const _Float16 bh = (_Float16)bias;
    h2 bb; bb.x = bh; bb.y = bh;
    const unsigned bias2 = __builtin_bit_cast(unsigned, bb);

    float psum_lo = 0.0f, psum_hi = 0.0f;
    float pmax_lo = -INFINITY, pmax_hi = -INFINITY;

    if (L <= 7)
        conv_all<7 >(xT2, sCh, sWs, n, d, offr, olen, bias2, bp, h, wid,
                     psum_lo, psum_hi, pmax_lo, pmax_hi);
    else if (L <= 9)
        conv_all<9 >(xT2, sCh, sWs, n, d, offr, olen, bias2, bp, h, wid,
                     psum_lo, psum_hi, pmax_lo, pmax_hi);
    else
        conv_all<11>(xT2, sCh, sWs, n, d, offr, olen, bias2, bp, h, wid,
                     psum_lo, psum_hi, pmax_lo, pmax_hi);

    sPlo[wid][lane] = psum_lo;
    sPhi[wid][lane] = psum_hi;
    sMlo[wid][lane] = pmax_lo;
    sMhi[wid][lane] = pmax_hi;
    __syncthreads();

    if (tid < 64) {
        const int b   = tid;           // batch
        const int bp2 = b >> 1;
        const int odd = b & 1;         // 0 -> lo half of pack, 1 -> hi
        float s = 0.0f, m = -INFINITY;
        #pragma unroll
        for (int w = 0; w < NW; ++w) {
            const float s0 = odd ? sPhi[w][bp2]      : sPlo[w][bp2];
            const float s1 = odd ? sPhi[w][32 + bp2] : sPlo[w][32 + bp2];
            const float m0 = odd ? sMhi[w][bp2]      : sMlo[w][bp2];
            const float m1 = odd ? sMhi[w][32 + bp2] : sMlo[w][32 + bp2];
            s += s0 + s1;
            m  = fmaxf(m, fmaxf(m0, m1));
        }
        const float inv_olen = 1.0f / (float)olen;
        out[(size_t)b * (2 * K_SZ) + 2 * k]     = s * inv_olen;
        out[(size_t)b * (2 * K_SZ) + 2 * k + 1] = m;
    }
}

// ---------------------------------------------------------------------------
// Fallback (ws too small): simple checked-gather kernel, known correct.
__global__ __launch_bounds__(256) void rocket_fallback(
    const float* __restrict__ x,
    const float* __restrict__ weights,
    const float* __restrict__ biases,
    const int*   __restrict__ ch_idx,
    const int*   __restrict__ dils,
    const int*   __restrict__ offs,
    const int*   __restrict__ olens,
    float*       __restrict__ out)
{
    __shared__ float sW[CMAX][LMAX];
    __shared__ int   sCh[CMAX];
    __shared__ float sRed[2][4];

    const int k   = blockIdx.x;
    const int tid = threadIdx.x;

    if (tid < CMAX * LMAX)
        sW[tid / LMAX][tid % LMAX] = weights[(size_t)k * (CMAX * LMAX) + tid];
    if (tid < CMAX)
        sCh[tid] = ch_idx[(size_t)k * CMAX + tid];
    __syncthreads();

    const int   d    = dils[k];
    const int   off  = offs[k] - PL_PAD;
    const int   olen = olens[k];
    const float bias = biases[k];
    const int   lane = tid & 63;
    const int   wid  = tid >> 6;

    for (int b = blockIdx.y; b < B_SZ; b += gridDim.y) {
        float psum = 0.0f, pmax = -INFINITY;
        for (int t = tid; t < T_SZ; t += 256) {
            float y = bias;
            for (int c = 0; c < CMAX; ++c) {
                const float* xb = x + ((size_t)b * C_SZ + sCh[c]) * T_SZ;
                int pos = off + t;
                for (int l = 0; l < LMAX; ++l) {
                    const float xv = ((unsigned)pos < (unsigned)T_SZ) ? xb[pos] : 0.0f;
                    y = fmaf(sW[c][l], xv, y);
                    pos += d;
                }
            }
            if (t < olen) {
                psum += 1.0f / (1.0f + __expf(3.0f - A_PARAM * y));
                pmax = fmaxf(pmax, y);
            }
        }
        for (int o = 32; o > 0; o >>= 1) {
            psum += __shfl_down(psum, o, 64);
            pmax  = fmaxf(pmax, __shfl_down(pmax, o, 64));
        }
        if (lane == 0) { sRed[0][wid] = psum; sRed[1][wid] = pmax; }
        __syncthreads();
        if (tid == 0) {
            const float s = sRed[0][0] + sRed[0][1] + sRed[0][2] + sRed[0][3];
            const float m = fmaxf(fmaxf(sRed[1][0], sRed[1][1]),
                                  fmaxf(sRed[1][2], sRed[1][3]));
            out[(size_t)b * (2 * K_SZ) + 2 * k]     = s / (float)olen;
            out[(size_t)b * (2 * K_SZ) + 2 * k + 1] = m;
        }
        __syncthreads();
    }
}

// ---------------------------------------------------------------------------
extern "C" void kernel_launch(void* const* d_in, const int* in_sizes, int n_in,
                              void* d_out, int out_size, void* d_ws, size_t ws_size,
                              hipStream_t stream) {
    const float* x       = (const float*)d_in[0];
    const float* weights = (const float*)d_in[1];
    const float* biases  = (const float*)d_in[2];
    const int*   ch_idx  = (const int*)  d_in[3];
    const int*   dils    = (const int*)  d_in[4];
    const int*   offs    = (const int*)  d_in[5];
    const int*   olens   = (const int*)  d_in[6];
    float*       out     = (float*)d_out;

    const size_t xt_bytes = (size_t)C_SZ * T_SZ * 32 * sizeof(unsigned); // 3.15 MB
    const size_t need     = xt_bytes + K_SZ * sizeof(unsigned);

    if (ws_size >= need) {
        unsigned* xT2  = (unsigned*)d_ws;
        unsigned* perm = (unsigned*)((char*)d_ws + xt_bytes);
        const int npk  = C_SZ * T_SZ * 32;
        trp_kernel<<<npk / 256, 256, 0, stream>>>(x, xT2);
        sched_kernel<<<1, 1024, 0, stream>>>(weights, olens, perm);
        rocket_tr<<<K_SZ, BLOCK_MAIN, 0, stream>>>(xT2, perm, weights, biases,
                                                   ch_idx, dils, offs, olens, out);
    } else {
        dim3 grid(K_SZ, 16);
        rocket_fallback<<<grid, 256, 0, stream>>>(x, weights, biases, ch_idx,
                                                  dils, offs, olens, out);
    }
}

// Round 13
// 859.555 us; speedup vs baseline: 1.1890x; 1.1890x over previous
//
#include <hip/hip_runtime.h>
#include <math.h>

// Problem constants (fixed by the reference setup)
#define B_SZ   64
#define C_SZ   12
#define T_SZ   2048
#define K_SZ   2048
#define LMAX   11
#define CMAX   11     // C-1
#define PL_PAD 1024
#define A_PARAM 7.0f

#define NW     8      // waves per block in main kernel
#define BLOCK_MAIN (NW * 64)
#define R      8      // outputs per half-wave per item (item covers 2R outputs)

typedef _Float16 h2 __attribute__((ext_vector_type(2)));

// v_pk_fma_f16 on raw u32 payloads — no ext_vector arrays, no unions, so all
// arrays stay SROA-able (rounds 8-12 lesson: type-punning constructs => scratch).
__device__ __forceinline__ unsigned pk_fma(unsigned a, unsigned b, unsigned c) {
    unsigned d;
    asm("v_pk_fma_f16 %0, %1, %2, %3" : "=v"(d) : "v"(a), "v"(b), "v"(c));
    return d;
}
__device__ __forceinline__ float lo_f(unsigned u) {
    return (float)__builtin_bit_cast(_Float16, (unsigned short)(u & 0xFFFFu));
}
__device__ __forceinline__ float hi_f(unsigned u) {
    return (float)__builtin_bit_cast(_Float16, (unsigned short)(u >> 16));
}

// ---------------------------------------------------------------------------
// Pack to batch-pair fp16: xT2[c][t][bp] = {fp16 x[2bp][c][t], fp16 x[2bp+1][c][t]}
// 12*2048*32 u32 = 3.15 MB -> per-XCD L2 resident.
__global__ __launch_bounds__(256) void trp_kernel(const float* __restrict__ x,
                                                  unsigned* __restrict__ xT2) {
    const int u  = blockIdx.x * 256 + threadIdx.x;   // [0, C*T*32)
    const int bp = u & 31;
    const int t  = (u >> 5) & (T_SZ - 1);
    const int c  = u >> 16;                          // T*32 = 65536 per channel
    const float a = x[((size_t)(2 * bp) * C_SZ + c) * T_SZ + t];
    const float b = x[((size_t)(2 * bp + 1) * C_SZ + c) * T_SZ + t];
    const unsigned ua = (unsigned)__builtin_bit_cast(unsigned short, (_Float16)a);
    const unsigned ub = (unsigned)__builtin_bit_cast(unsigned short, (_Float16)b);
    xT2[u] = ua | (ub << 16);
}

// ---------------------------------------------------------------------------
// Schedule: cost[k] ~ n*L*ceil(olen/128). Bitonic sort descending (LPT).
__global__ __launch_bounds__(1024) void sched_kernel(const float* __restrict__ w,
                                                     const int* __restrict__ olens,
                                                     unsigned* __restrict__ perm) {
    __shared__ unsigned key[K_SZ];
    const int tid = threadIdx.x;

    for (int k = tid; k < K_SZ; k += 1024) {
        const float* wk = w + (size_t)k * (CMAX * LMAX);
        int n = 0, L = 0;
        for (int e = 0; e < CMAX * LMAX; ++e) {
            if (wk[e] != 0.0f) {
                const int c = e / LMAX, l = e % LMAX;
                n = max(n, c + 1);
                L = max(L, l + 1);
            }
        }
        const unsigned cost = (unsigned)(n * L) * (unsigned)((olens[k] + 127) >> 7);
        key[k] = (cost << 11) | (unsigned)k;
    }
    __syncthreads();

    for (int ksz = 2; ksz <= K_SZ; ksz <<= 1) {
        for (int j = ksz >> 1; j > 0; j >>= 1) {
            for (int i = tid; i < K_SZ; i += 1024) {
                const int ixj = i ^ j;
                if (ixj > i) {
                    const unsigned a = key[i], b = key[ixj];
                    const bool sw = ((i & ksz) == 0) ? (a < b) : (a > b); // descending
                    if (sw) { key[i] = b; key[ixj] = a; }
                }
            }
            __syncthreads();
        }
    }
    for (int i = tid; i < K_SZ; i += 1024)
        perm[i] = key[i] & 0x7FFu;
}

// ---------------------------------------------------------------------------
// Batch-pair pk_fma scheme. Wave lane = h*32 + bp:
//   bp in [0,32): batches {2bp, 2bp+1} packed in one u32 (fp16x2)
//   h in {0,1}:   outputs r + 8h of a 16-output item
// Per channel-item: NV u32 wave-loads (128 batch-values each), LC*R pk_fma.
template<int LC>
__device__ __forceinline__ void conv_all(
    const unsigned* __restrict__ xT2,
    const int*      __restrict__ sCh,
    const unsigned  (* __restrict__ sWs)[LMAX],  // splat {w,w} fp16 pairs
    int n, int d, int offr, int olen, unsigned bias2,
    int bp, int h, int wid,
    float& psum_lo, float& psum_hi, float& pmax_lo, float& pmax_hi)
{
    constexpr int NV   = R + LC - 1;          // taps per half
    constexpr int SPAN = 2 * R + LC - 2;      // max tap index across halves

    const int nj   = (olen + d - 1) / d;              // outputs per residue chain
    const int njb  = (nj + 2 * R - 1) / (2 * R);      // 16-output items per chain
    const int S    = (d >= 64) ? 1 : ((64 + d - 1) / d);
    const int len  = (njb + S - 1) / S;
    const int nunits = d * S;

    const int h8d   = h * (d << 3);           // tap/output shift for half h
    const int voffe = h * (d << 8) + bp;      // fast-path per-lane element offset

    for (int u = wid; u < nunits; u += NW) {
        int q, seg;
        if (S == 1) { q = u; seg = 0; }
        else        { q = u % d; seg = u / d; }       // wave-uniform div
        const int jb0 = seg * len;
        const int jb1 = min(njb, jb0 + len);

        for (int jb = jb0; jb < jb1; ++jb) {
            const int tq = q + jb * (2 * R * d);      // first output t (h=0)
            if (tq >= olen) break;
            const int tpos0 = tq + offr;              // real x coord of tap 0

            unsigned y[R];
            #pragma unroll
            for (int r = 0; r < R; ++r) y[r] = bias2;

            const bool fast = (tpos0 >= 0) && (tpos0 + SPAN * d < T_SZ);

            if (fast) {
                for (int c = 0; c < n; ++c) {
                    const int rb = __builtin_amdgcn_readfirstlane(sCh[c] * T_SZ + tpos0);
                    const unsigned* rp = xT2 + ((size_t)rb << 5);   // uniform base

                    unsigned vp2[NV];
                    #pragma unroll
                    for (int i = 0; i < NV; ++i) {
                        vp2[i] = rp[voffe];                         // saddr + voff
                        rp += (d << 5);                             // SALU bump
                    }
                    const unsigned* wrow = &sWs[c][0];
                    #pragma unroll
                    for (int l = 0; l < LC; ++l) {
                        const unsigned w = wrow[l];                 // LDS broadcast
                        #pragma unroll
                        for (int r = 0; r < R; ++r)
                            y[r] = pk_fma(w, vp2[l + r], y[r]);
                    }
                }
            } else {
                for (int c = 0; c < n; ++c) {
                    const int rbs = __builtin_amdgcn_readfirstlane(sCh[c] * T_SZ);
                    const unsigned* row = xT2 + ((size_t)rbs << 5);

                    unsigned vp2[NV];
                    #pragma unroll
                    for (int i = 0; i < NV; ++i) {
                        const int tp  = tpos0 + i * d + h8d;        // per-lane (h)
                        const int tpc = min(max(tp, 0), T_SZ - 1);
                        const unsigned v = row[(tpc << 5) + bp];
                        vp2[i] = ((unsigned)tp < (unsigned)T_SZ) ? v : 0u;
                    }
                    const unsigned* wrow = &sWs[c][0];
                    #pragma unroll
                    for (int l = 0; l < LC; ++l) {
                        const unsigned w = wrow[l];
                        #pragma unroll
                        for (int r = 0; r < R; ++r)
                            y[r] = pk_fma(w, vp2[l + r], y[r]);
                    }
                }
            }

            #pragma unroll
            for (int r = 0; r < R; ++r) {
                const int tl = tq + r * d + h8d;      // this half's output t
                if (tl < olen) {                      // per-lane predication
                    const float ylo = lo_f(y[r]);
                    const float yhi = hi_f(y[r]);
                    psum_lo += 1.0f / (1.0f + __expf(3.0f - A_PARAM * ylo));
                    psum_hi += 1.0f / (1.0f + __expf(3.0f - A_PARAM * yhi));
                    pmax_lo  = fmaxf(pmax_lo, ylo);
                    pmax_hi  = fmaxf(pmax_hi, yhi);
                }
            }
        }
    }
}

__global__ __launch_bounds__(BLOCK_MAIN, 8) void rocket_tr(
    const unsigned* __restrict__ xT2,        // (C, T, 32) fp16 batch pairs
    const unsigned* __restrict__ perm,       // heavy-first block -> k map
    const float* __restrict__ weights,       // (K, CMAX, LMAX)
    const float* __restrict__ biases,
    const int*   __restrict__ ch_idx,        // (K, CMAX)
    const int*   __restrict__ dils,
    const int*   __restrict__ offs,
    const int*   __restrict__ olens,
    float*       __restrict__ out)           // (B, 2K)
{
    __shared__ float    sW[CMAX][LMAX];
    __shared__ unsigned sWs[CMAX][LMAX];     // splat {w,w} fp16 pairs
    __shared__ int      sCh[CMAX];
    __shared__ int      sMeta[2];
    __shared__ float    sPlo[NW][64];
    __shared__ float    sPhi[NW][64];
    __shared__ float    sMlo[NW][64];
    __shared__ float    sMhi[NW][64];

    const int k   = (int)perm[blockIdx.x];
    const int tid = threadIdx.x;

    if (tid < CMAX * LMAX)
        sW[tid / LMAX][tid % LMAX] = weights[(size_t)k * (CMAX * LMAX) + tid];
    if (tid < CMAX)
        sCh[tid] = ch_idx[(size_t)k * CMAX + tid];
    __syncthreads();

    if (tid < CMAX * LMAX) {
        const int c = tid / LMAX, l = tid % LMAX;
        const unsigned wh =
            (unsigned)__builtin_bit_cast(unsigned short, (_Float16)sW[c][l]);
        sWs[c][l] = wh | (wh << 16);
    }
    if (tid == 0) {
        // Effective channel/tap counts (zero-padded rows/taps contribute 0).
        int n = 0, L = 0;
        for (int c = 0; c < CMAX; ++c) {
            bool nz = false;
            for (int l = 0; l < LMAX; ++l) {
                if (sW[c][l] != 0.0f) { nz = true; if (l + 1 > L) L = l + 1; }
            }
            if (nz) n = c + 1;
        }
        sMeta[0] = n; sMeta[1] = L;
    }
    __syncthreads();

    const int   n    = sMeta[0];
    const int   L    = sMeta[1];
    const int   d    = dils[k];
    const int   offr = offs[k] - PL_PAD;   // real x coord offset (may be <0)
    const int   olen = olens[k];
    const float bias = biases[k];
    const int   lane = tid & 63;
    const int   bp   = lane & 31;
    const int   h    = lane >> 5;
    const int   wid  = __builtin_amdgcn_readfirstlane(tid >> 6);

    const unsigned bh =
        (unsigned)__builtin_bit_cast(unsigned short, (_Float16)bias);
    const unsigned bias2 = bh | (bh << 16);

    float psum_lo = 0.0f, psum_hi = 0.0f;
    float pmax_lo = -INFINITY, pmax_hi = -INFINITY;

    if (L <= 7)
        conv_all<7 >(xT2, sCh, sWs, n, d, offr, olen, bias2, bp, h, wid,
                     psum_lo, psum_hi, pmax_lo, pmax_hi);
    else if (L <= 9)
        conv_all<9 >(xT2, sCh, sWs, n, d, offr, olen, bias2, bp, h, wid,
                     psum_lo, psum_hi, pmax_lo, pmax_hi);
    else
        conv_all<11>(xT2, sCh, sWs, n, d, offr, olen, bias2, bp, h, wid,
                     psum_lo, psum_hi, pmax_lo, pmax_hi);

    sPlo[wid][lane] = psum_lo;
    sPhi[wid][lane] = psum_hi;
    sMlo[wid][lane] = pmax_lo;
    sMhi[wid][lane] = pmax_hi;
    __syncthreads();

    if (tid < 64) {
        const int b   = tid;           // batch
        const int bp2 = b >> 1;
        const int odd = b & 1;         // 0 -> lo half of pack, 1 -> hi
        float s = 0.0f, m = -INFINITY;
        #pragma unroll
        for (int w = 0; w < NW; ++w) {
            const float s0 = odd ? sPhi[w][bp2]      : sPlo[w][bp2];
            const float s1 = odd ? sPhi[w][32 + bp2] : sPlo[w][32 + bp2];
            const float m0 = odd ? sMhi[w][bp2]      : sMlo[w][bp2];
            const float m1 = odd ? sMhi[w][32 + bp2] : sMlo[w][32 + bp2];
            s += s0 + s1;
            m  = fmaxf(m, fmaxf(m0, m1));
        }
        const float inv_olen = 1.0f / (float)olen;
        out[(size_t)b * (2 * K_SZ) + 2 * k]     = s * inv_olen;
        out[(size_t)b * (2 * K_SZ) + 2 * k + 1] = m;
    }
}

// ---------------------------------------------------------------------------
// Fallback (ws too small): simple checked-gather kernel, known correct.
__global__ __launch_bounds__(256) void rocket_fallback(
    const float* __restrict__ x,
    const float* __restrict__ weights,
    const float* __restrict__ biases,
    const int*   __restrict__ ch_idx,
    const int*   __restrict__ dils,
    const int*   __restrict__ offs,
    const int*   __restrict__ olens,
    float*       __restrict__ out)
{
    __shared__ float sW[CMAX][LMAX];
    __shared__ int   sCh[CMAX];
    __shared__ float sRed[2][4];

    const int k   = blockIdx.x;
    const int tid = threadIdx.x;

    if (tid < CMAX * LMAX)
        sW[tid / LMAX][tid % LMAX] = weights[(size_t)k * (CMAX * LMAX) + tid];
    if (tid < CMAX)
        sCh[tid] = ch_idx[(size_t)k * CMAX + tid];
    __syncthreads();

    const int   d    = dils[k];
    const int   off  = offs[k] - PL_PAD;
    const int   olen = olens[k];
    const float bias = biases[k];
    const int   lane = tid & 63;
    const int   wid  = tid >> 6;

    for (int b = blockIdx.y; b < B_SZ; b += gridDim.y) {
        float psum = 0.0f, pmax = -INFINITY;
        for (int t = tid; t < T_SZ; t += 256) {
            float y = bias;
            for (int c = 0; c < CMAX; ++c) {
                const float* xb = x + ((size_t)b * C_SZ + sCh[c]) * T_SZ;
                int pos = off + t;
                for (int l = 0; l < LMAX; ++l) {
                    const float xv = ((unsigned)pos < (unsigned)T_SZ) ? xb[pos] : 0.0f;
                    y = fmaf(sW[c][l], xv, y);
                    pos += d;
                }
            }
            if (t < olen) {
                psum += 1.0f / (1.0f + __expf(3.0f - A_PARAM * y));
                pmax = fmaxf(pmax, y);
            }
        }
        for (int o = 32; o > 0; o >>= 1) {
            psum += __shfl_down(psum, o, 64);
            pmax  = fmaxf(pmax, __shfl_down(pmax, o, 64));
        }
        if (lane == 0) { sRed[0][wid] = psum; sRed[1][wid] = pmax; }
        __syncthreads();
        if (tid == 0) {
            const float s = sRed[0][0] + sRed[0][1] + sRed[0][2] + sRed[0][3];
            const float m = fmaxf(fmaxf(sRed[1][0], sRed[1][1]),
                                  fmaxf(sRed[1][2], sRed[1][3]));
            out[(size_t)b * (2 * K_SZ) + 2 * k]     = s / (float)olen;
            out[(size_t)b * (2 * K_SZ) + 2 * k + 1] = m;
        }
        __syncthreads();
    }
}

// ---------------------------------------------------------------------------
extern "C" void kernel_launch(void* const* d_in, const int* in_sizes, int n_in,
                              void* d_out, int out_size, void* d_ws, size_t ws_size,
                              hipStream_t stream) {
    const float* x       = (const float*)d_in[0];
    const float* weights = (const float*)d_in[1];
    const float* biases  = (const float*)d_in[2];
    const int*   ch_idx  = (const int*)  d_in[3];
    const int*   dils    = (const int*)  d_in[4];
    const int*   offs    = (const int*)  d_in[5];
    const int*   olens   = (const int*)  d_in[6];
    float*       out     = (float*)d_out;

    const size_t xt_bytes = (size_t)C_SZ * T_SZ * 32 * sizeof(unsigned); // 3.15 MB
    const size_t need     = xt_bytes + K_SZ * sizeof(unsigned);

    if (ws_size >= need) {
        unsigned* xT2  = (unsigned*)d_ws;
        unsigned* perm = (unsigned*)((char*)d_ws + xt_bytes);
        const int npk  = C_SZ * T_SZ * 32;
        trp_kernel<<<npk / 256, 256, 0, stream>>>(x, xT2);
        sched_kernel<<<1, 1024, 0, stream>>>(weights, olens, perm);
        rocket_tr<<<K_SZ, BLOCK_MAIN, 0, stream>>>(xT2, perm, weights, biases,
                                                   ch_idx, dils, offs, olens, out);
    } else {
        dim3 grid(K_SZ, 16);
        rocket_fallback<<<grid, 256, 0, stream>>>(x, weights, biases, ch_idx,
                                                  dils, offs, olens, out);
    }
}

// Round 14
// 845.540 us; speedup vs baseline: 1.2088x; 1.0166x over previous
//
#include <hip/hip_runtime.h>
#include <math.h>

// Problem constants (fixed by the reference setup)
#define B_SZ   64
#define C_SZ   12
#define T_SZ   2048
#define K_SZ   2048
#define LMAX   11
#define CMAX   11     // C-1
#define PL_PAD 1024
#define A_PARAM 7.0f

#define NW     8      // waves per block in main kernel
#define BLOCK_MAIN (NW * 64)
#define R      8      // outputs per item

typedef _Float16 h2 __attribute__((ext_vector_type(2)));

// Scalar h2 ops on u32 payloads. Arrays stay 'unsigned' everywhere (rounds
// 8-13 lesson: unions / vector-typed ARRAYS / inline-asm => scratch spills).
__device__ __forceinline__ unsigned fma2u(unsigned w, unsigned v, unsigned acc) {
    const h2 r = __builtin_elementwise_fma(__builtin_bit_cast(h2, w),
                                           __builtin_bit_cast(h2, v),
                                           __builtin_bit_cast(h2, acc));
    return __builtin_bit_cast(unsigned, r);
}
__device__ __forceinline__ unsigned add2u(unsigned a, unsigned b) {
    const h2 r = __builtin_bit_cast(h2, a) + __builtin_bit_cast(h2, b);
    return __builtin_bit_cast(unsigned, r);
}
__device__ __forceinline__ float lo_f(unsigned u) {
    return (float)__builtin_bit_cast(_Float16, (unsigned short)(u & 0xFFFFu));
}
__device__ __forceinline__ float hi_f(unsigned u) {
    return (float)__builtin_bit_cast(_Float16, (unsigned short)(u >> 16));
}

// ---------------------------------------------------------------------------
// Transpose to fp16: xT[c][t][b] = fp16(x[b][c][t]). 3.15 MB -> per-XCD L2.
// Viewed as u32: xT2[c][t][bp] = {batch 2bp, batch 2bp+1}.
__global__ __launch_bounds__(256) void trh_kernel(const float* __restrict__ x,
                                                  unsigned short* __restrict__ xT) {
    const int c    = blockIdx.x;
    const int lane = threadIdx.x & 63;
    const int wid  = threadIdx.x >> 6;
    const int t0   = blockIdx.y * 128 + wid * 32;
    const float* xrow = x + ((size_t)lane * C_SZ + c) * T_SZ + t0;
    unsigned short* dst = xT + ((size_t)c * T_SZ + t0) * 64 + lane;
    #pragma unroll 8
    for (int i = 0; i < 32; ++i) {
        const _Float16 h = (_Float16)xrow[i];
        dst[i * 64] = __builtin_bit_cast(unsigned short, h);
    }
}

// ---------------------------------------------------------------------------
// Schedule: cost[k] ~ n*L*ceil(olen/128). Bitonic sort descending (LPT).
__global__ __launch_bounds__(1024) void sched_kernel(const float* __restrict__ w,
                                                     const int* __restrict__ olens,
                                                     unsigned* __restrict__ perm) {
    __shared__ unsigned key[K_SZ];
    const int tid = threadIdx.x;

    for (int k = tid; k < K_SZ; k += 1024) {
        const float* wk = w + (size_t)k * (CMAX * LMAX);
        int n = 0, L = 0;
        for (int e = 0; e < CMAX * LMAX; ++e) {
            if (wk[e] != 0.0f) {
                const int c = e / LMAX, l = e % LMAX;
                n = max(n, c + 1);
                L = max(L, l + 1);
            }
        }
        const unsigned cost = (unsigned)(n * L) * (unsigned)((olens[k] + 127) >> 7);
        key[k] = (cost << 11) | (unsigned)k;
    }
    __syncthreads();

    for (int ksz = 2; ksz <= K_SZ; ksz <<= 1) {
        for (int j = ksz >> 1; j > 0; j >>= 1) {
            for (int i = tid; i < K_SZ; i += 1024) {
                const int ixj = i ^ j;
                if (ixj > i) {
                    const unsigned a = key[i], b = key[ixj];
                    const bool sw = ((i & ksz) == 0) ? (a < b) : (a > b); // descending
                    if (sw) { key[i] = b; key[ixj] = a; }
                }
            }
            __syncthreads();
        }
    }
    for (int i = tid; i < K_SZ; i += 1024)
        perm[i] = key[i] & 0x7FFu;
}

// ---------------------------------------------------------------------------
// Channel-split batch-pack scheme. Lane = h*32 + bp:
//   bp: batches {2bp, 2bp+1} in one u32;  h: which channel of the pass pair.
// One pass = 2 channels x 8 outputs x 64 batches: 18 wave-loads + 88 pk_fma.
// Halves combined per item via shfl_xor(32) + pk_add before sigmoid (h==0).
template<int LC>
__device__ __forceinline__ void conv_all(
    const unsigned* __restrict__ xT2,
    const int*      __restrict__ sChOff,       // [12] channel row elem offsets
    const unsigned  (* __restrict__ sWs)[LMAX],// [12][LMAX] splat {w,w} (row 11 = 0)
    int npass, int d, int offr, int olen, unsigned yinit,
    int bp, int h, int wid,
    float& psum_lo, float& psum_hi, float& pmax_lo, float& pmax_hi)
{
    constexpr int NV = R + LC - 1;            // taps spanned by one item

    const int nj   = (olen + d - 1) / d;      // outputs per residue chain
    const int njb  = (nj + R - 1) / R;        // items per chain
    const int S    = (d >= 64) ? 1 : ((64 + d - 1) / d);
    const int len  = (njb + S - 1) / S;
    const int nunits = d * S;
    const int d32  = d * 32;

    for (int u = wid; u < nunits; u += NW) {
        int q, seg;
        if (S == 1) { q = u; seg = 0; }
        else        { q = u % d; seg = u / d; }   // wave-uniform div
        const int jb0 = seg * len;
        const int jb1 = min(njb, jb0 + len);

        for (int jb = jb0; jb < jb1; ++jb) {
            const int tq = q + jb * (R * d);      // first output t of this item
            if (tq >= olen) break;
            const int tpos0 = tq + offr;          // real x coord of tap 0

            unsigned y[R];
            #pragma unroll
            for (int r = 0; r < R; ++r) y[r] = yinit;

            const bool fast = (tpos0 >= 0) && (tpos0 + (NV - 1) * d < T_SZ);

            if (fast) {
                const unsigned* rpbase =
                    xT2 + (size_t)__builtin_amdgcn_readfirstlane(tpos0) * 32;
                for (int p = 0; p < npass; ++p) {
                    const int voff = sChOff[2 * p + h] + bp;   // per-lane (LDS)
                    const unsigned* rp = rpbase;
                    unsigned vp[NV];
                    #pragma unroll
                    for (int i = 0; i < NV; ++i) {
                        vp[i] = rp[voff];                      // saddr + voff
                        rp += d32;                             // SALU bump
                    }
                    const unsigned* wrow = &sWs[2 * p + h][0];
                    #pragma unroll
                    for (int l = 0; l < LC; ++l) {
                        const unsigned wl = wrow[l];           // LDS broadcast
                        #pragma unroll
                        for (int r = 0; r < R; ++r)
                            y[r] = fma2u(wl, vp[l + r], y[r]);
                    }
                }
            } else {
                for (int p = 0; p < npass; ++p) {
                    const int voff = sChOff[2 * p + h] + bp;
                    unsigned vp[NV];
                    #pragma unroll
                    for (int i = 0; i < NV; ++i) {
                        const int tp  = tpos0 + i * d;         // wave-uniform
                        const int tpc = min(max(tp, 0), T_SZ - 1);
                        const unsigned* rp =
                            xT2 + (size_t)__builtin_amdgcn_readfirstlane(tpc) * 32;
                        const unsigned v = rp[voff];
                        vp[i] = ((unsigned)tp < (unsigned)T_SZ) ? v : 0u;
                    }
                    const unsigned* wrow = &sWs[2 * p + h][0];
                    #pragma unroll
                    for (int l = 0; l < LC; ++l) {
                        const unsigned wl = wrow[l];
                        #pragma unroll
                        for (int r = 0; r < R; ++r)
                            y[r] = fma2u(wl, vp[l + r], y[r]);
                    }
                }
            }

            // Combine channel halves, then sigmoid/max on h==0 lanes only.
            #pragma unroll
            for (int r = 0; r < R; ++r) {
                const unsigned yo = (unsigned)__shfl_xor((int)y[r], 32, 64);
                const int tl = tq + r * d;                    // uniform
                if (h == 0 && tl < olen) {
                    const unsigned yc = add2u(y[r], yo);
                    const float ylo = lo_f(yc);
                    const float yhi = hi_f(yc);
                    psum_lo += 1.0f / (1.0f + __expf(3.0f - A_PARAM * ylo));
                    psum_hi += 1.0f / (1.0f + __expf(3.0f - A_PARAM * yhi));
                    pmax_lo  = fmaxf(pmax_lo, ylo);
                    pmax_hi  = fmaxf(pmax_hi, yhi);
                }
            }
        }
    }
}

__global__ __launch_bounds__(BLOCK_MAIN, 8) void rocket_tr(
    const unsigned* __restrict__ xT2,        // (C, T, 32) fp16 batch pairs
    const unsigned* __restrict__ perm,       // heavy-first block -> k map
    const float* __restrict__ weights,       // (K, CMAX, LMAX)
    const float* __restrict__ biases,
    const int*   __restrict__ ch_idx,        // (K, CMAX)
    const int*   __restrict__ dils,
    const int*   __restrict__ offs,
    const int*   __restrict__ olens,
    float*       __restrict__ out)           // (B, 2K)
{
    __shared__ float    sW[CMAX][LMAX];
    __shared__ unsigned sWs[12][LMAX];       // splat {w,w}; row 11 zeroed
    __shared__ int      sChOff[12];          // channel row element offsets
    __shared__ int      sMeta[2];
    __shared__ float    sPlo[NW][64];
    __shared__ float    sPhi[NW][64];
    __shared__ float    sMlo[NW][64];
    __shared__ float    sMhi[NW][64];

    const int k   = (int)perm[blockIdx.x];
    const int tid = threadIdx.x;

    if (tid < CMAX * LMAX)
        sW[tid / LMAX][tid % LMAX] = weights[(size_t)k * (CMAX * LMAX) + tid];
    if (tid < 12)
        sChOff[tid] = (tid < CMAX) ? ch_idx[(size_t)k * CMAX + tid] * (T_SZ * 32) : 0;
    __syncthreads();

    if (tid < 12 * LMAX) {
        const int c = tid / LMAX, l = tid % LMAX;
        const float wf = (c < CMAX) ? sW[c][l] : 0.0f;
        const unsigned wh =
            (unsigned)__builtin_bit_cast(unsigned short, (_Float16)wf);
        sWs[c][l] = wh | (wh << 16);
    }
    if (tid == 0) {
        // Effective channel/tap counts (zero-padded rows/taps contribute 0).
        int n = 0, L = 0;
        for (int c = 0; c < CMAX; ++c) {
            bool nz = false;
            for (int l = 0; l < LMAX; ++l) {
                if (sW[c][l] != 0.0f) { nz = true; if (l + 1 > L) L = l + 1; }
            }
            if (nz) n = c + 1;
        }
        sMeta[0] = n; sMeta[1] = L;
    }
    __syncthreads();

    const int   n     = sMeta[0];
    const int   L     = sMeta[1];
    const int   npass = (n + 1) >> 1;
    const int   d     = dils[k];
    const int   offr  = offs[k] - PL_PAD;  // real x coord offset (may be <0)
    const int   olen  = olens[k];
    const float bias  = biases[k];
    const int   lane  = tid & 63;
    const int   bp    = lane & 31;
    const int   h     = lane >> 5;
    const int   wid   = __builtin_amdgcn_readfirstlane(tid >> 6);

    const unsigned bh =
        (unsigned)__builtin_bit_cast(unsigned short, (_Float16)bias);
    const unsigned yinit = h ? 0u : (bh | (bh << 16));   // bias once (h=0 only)

    float psum_lo = 0.0f, psum_hi = 0.0f;
    float pmax_lo = -INFINITY, pmax_hi = -INFINITY;

    if (L <= 7)
        conv_all<7 >(xT2, sChOff, sWs, npass, d, offr, olen, yinit, bp, h, wid,
                     psum_lo, psum_hi, pmax_lo, pmax_hi);
    else if (L <= 9)
        conv_all<9 >(xT2, sChOff, sWs, npass, d, offr, olen, yinit, bp, h, wid,
                     psum_lo, psum_hi, pmax_lo, pmax_hi);
    else
        conv_all<11>(xT2, sChOff, sWs, npass, d, offr, olen, yinit, bp, h, wid,
                     psum_lo, psum_hi, pmax_lo, pmax_hi);

    sPlo[wid][lane] = psum_lo;    // h=1 lanes hold 0 / -inf (harmless)
    sPhi[wid][lane] = psum_hi;
    sMlo[wid][lane] = pmax_lo;
    sMhi[wid][lane] = pmax_hi;
    __syncthreads();

    if (tid < 64) {
        const int b   = tid;           // batch
        const int bp2 = b >> 1;
        const int odd = b & 1;         // 0 -> lo half of pack, 1 -> hi
        float s = 0.0f, m = -INFINITY;
        #pragma unroll
        for (int w = 0; w < NW; ++w) {
            const float s0 = odd ? sPhi[w][bp2]      : sPlo[w][bp2];
            const float s1 = odd ? sPhi[w][32 + bp2] : sPlo[w][32 + bp2];
            const float m0 = odd ? sMhi[w][bp2]      : sMlo[w][bp2];
            const float m1 = odd ? sMhi[w][32 + bp2] : sMlo[w][32 + bp2];
            s += s0 + s1;
            m  = fmaxf(m, fmaxf(m0, m1));
        }
        const float inv_olen = 1.0f / (float)olen;
        out[(size_t)b * (2 * K_SZ) + 2 * k]     = s * inv_olen;
        out[(size_t)b * (2 * K_SZ) + 2 * k + 1] = m;
    }
}

// ---------------------------------------------------------------------------
// Fallback (ws too small): simple checked-gather kernel, known correct.
__global__ __launch_bounds__(256) void rocket_fallback(
    const float* __restrict__ x,
    const float* __restrict__ weights,
    const float* __restrict__ biases,
    const int*   __restrict__ ch_idx,
    const int*   __restrict__ dils,
    const int*   __restrict__ offs,
    const int*   __restrict__ olens,
    float*       __restrict__ out)
{
    __shared__ float sW[CMAX][LMAX];
    __shared__ int   sCh[CMAX];
    __shared__ float sRed[2][4];

    const int k   = blockIdx.x;
    const int tid = threadIdx.x;

    if (tid < CMAX * LMAX)
        sW[tid / LMAX][tid % LMAX] = weights[(size_t)k * (CMAX * LMAX) + tid];
    if (tid < CMAX)
        sCh[tid] = ch_idx[(size_t)k * CMAX + tid];
    __syncthreads();

    const int   d    = dils[k];
    const int   off  = offs[k] - PL_PAD;
    const int   olen = olens[k];
    const float bias = biases[k];
    const int   lane = tid & 63;
    const int   wid  = tid >> 6;

    for (int b = blockIdx.y; b < B_SZ; b += gridDim.y) {
        float psum = 0.0f, pmax = -INFINITY;
        for (int t = tid; t < T_SZ; t += 256) {
            float y = bias;
            for (int c = 0; c < CMAX; ++c) {
                const float* xb = x + ((size_t)b * C_SZ + sCh[c]) * T_SZ;
                int pos = off + t;
                for (int l = 0; l < LMAX; ++l) {
                    const float xv = ((unsigned)pos < (unsigned)T_SZ) ? xb[pos] : 0.0f;
                    y = fmaf(sW[c][l], xv, y);
                    pos += d;
                }
            }
            if (t < olen) {
                psum += 1.0f / (1.0f + __expf(3.0f - A_PARAM * y));
                pmax = fmaxf(pmax, y);
            }
        }
        for (int o = 32; o > 0; o >>= 1) {
            psum += __shfl_down(psum, o, 64);
            pmax  = fmaxf(pmax, __shfl_down(pmax, o, 64));
        }
        if (lane == 0) { sRed[0][wid] = psum; sRed[1][wid] = pmax; }
        __syncthreads();
        if (tid == 0) {
            const float s = sRed[0][0] + sRed[0][1] + sRed[0][2] + sRed[0][3];
            const float m = fmaxf(fmaxf(sRed[1][0], sRed[1][1]),
                                  fmaxf(sRed[1][2], sRed[1][3]));
            out[(size_t)b * (2 * K_SZ) + 2 * k]     = s / (float)olen;
            out[(size_t)b * (2 * K_SZ) + 2 * k + 1] = m;
        }
        __syncthreads();
    }
}

// ---------------------------------------------------------------------------
extern "C" void kernel_launch(void* const* d_in, const int* in_sizes, int n_in,
                              void* d_out, int out_size, void* d_ws, size_t ws_size,
                              hipStream_t stream) {
    const float* x       = (const float*)d_in[0];
    const float* weights = (const float*)d_in[1];
    const float* biases  = (const float*)d_in[2];
    const int*   ch_idx  = (const int*)  d_in[3];
    const int*   dils    = (const int*)  d_in[4];
    const int*   offs    = (const int*)  d_in[5];
    const int*   olens   = (const int*)  d_in[6];
    float*       out     = (float*)d_out;

    const size_t xt_bytes = (size_t)C_SZ * T_SZ * 64 * sizeof(unsigned short); // 3.15 MB
    const size_t need     = xt_bytes + K_SZ * sizeof(unsigned);

    if (ws_size >= need) {
        unsigned short* xT = (unsigned short*)d_ws;
        unsigned* perm     = (unsigned*)((char*)d_ws + xt_bytes);
        dim3 tgrid(C_SZ, T_SZ / 128);
        trh_kernel<<<tgrid, 256, 0, stream>>>(x, xT);
        sched_kernel<<<1, 1024, 0, stream>>>(weights, olens, perm);
        rocket_tr<<<K_SZ, BLOCK_MAIN, 0, stream>>>((const unsigned*)xT, perm,
                                                   weights, biases, ch_idx,
                                                   dils, offs, olens, out);
    } else {
        dim3 grid(K_SZ, 16);
        rocket_fallback<<<grid, 256, 0, stream>>>(x, weights, biases, ch_idx,
                                                  dils, offs, olens, out);
    }
}